// Round 7
// baseline (174.011 us; speedup 1.0000x reference)
//
#include <hip/hip_runtime.h>
#include <cstdint>
#include <cstddef>

// B=32 batch, K=4096 complex input pixels, N=4096 complex outputs.
// out[b,n] = sum_k (e_in[b,k]*ts[k]) * w[k,n]   (complex)
// Real-GEMM formulation, K'=8192 interleaved (re,im):
//   A[b][2k]=m_re, A[b][2k+1]=m_im
//   B_re[2k][n]=w_re, B_re[2k+1][n]=-w_im  -> out_re
//   B_im[2k][n]=w_im, B_im[2k+1][n]= w_re  -> out_im
// OUTPUT (established R5): float32 PLANAR — [re-plane 131072][im-plane 131072].
#define KC 4096
#define NN 4096
#define NB 32
#define HALF (NB * NN)

typedef __attribute__((ext_vector_type(8))) short  bf16x8;  // 8 bf16 (4 VGPRs)
typedef __attribute__((ext_vector_type(16))) float f32x16;  // 32x32 MFMA acc

__device__ __forceinline__ uint32_t f2bf(float f) {
    // round-to-nearest-even fp32 -> bf16, returned in low 16 bits
    union { float f; unsigned u; } v; v.f = f;
    unsigned r = v.u + 0x7fffu + ((v.u >> 16) & 1u);
    return r >> 16;
}

// ---------------------------------------------------------------------------
// Kernel 1: modulated[b,k] = e_in[b,k] * (sigmoid(amp[k]) * exp(i*phase[k]))
// bf16 pairs in MFMA-A octet order (verified): dword idx = ((k>>2)*32+b)*4+(k&3)
// ---------------------------------------------------------------------------
__global__ __launch_bounds__(256) void prep_kernel(
    const float* __restrict__ in_re, const float* __restrict__ in_im,
    const float* __restrict__ amp,   const float* __restrict__ phase,
    uint32_t* __restrict__ wsA)
{
    int tid = blockIdx.x * 256 + threadIdx.x;   // 32*4096 threads
    int b = tid >> 12;
    int k = tid & (KC - 1);
    float er = in_re[tid], ei = in_im[tid];
    float a = amp[k], p = phase[k];
    float s = 1.0f / (1.0f + expf(-a));
    float sn, cs;
    sincosf(p, &sn, &cs);
    float tr = s * cs, ti = s * sn;
    float mr = er * tr - ei * ti;
    float mi = er * ti + ei * tr;
    uint32_t pk = f2bf(mr) | (f2bf(mi) << 16);
    wsA[((((k >> 2) << 5) + b) << 2) | (k & 3)] = pk;
}

// ---------------------------------------------------------------------------
// Kernel 2: split-K complex GEMM, 2x mfma_f32_32x32x16_bf16 per step,
// manual register double-buffer: step t+1's 9 loads issue before step t's
// pack+MFMA consume their (already-resident) registers.
// ---------------------------------------------------------------------------
__global__ __launch_bounds__(256, 4) void gemm_kernel(
    const float* __restrict__ w_re, const float* __restrict__ w_im,
    const bf16x8* __restrict__ wsA, float2* __restrict__ wsP, int steps)
{
    const int lane = threadIdx.x & 63;
    const int wave = threadIdx.x >> 6;
    const int h    = lane >> 5;
    const int l32  = lane & 31;
    const int n    = blockIdx.x * 128 + wave * 32 + l32;
    const int s    = blockIdx.y;
    const int kbase = s * (steps * 8);   // complex-k base of this split

    f32x16 accR = {};
    f32x16 accI = {};

    const bf16x8* aptr = wsA + ((size_t)(kbase >> 2) + h) * 32 + l32;
    const float* pre = w_re + (size_t)(kbase + h * 4) * NN + n;
    const float* pim = w_im + (size_t)(kbase + h * 4) * NN + n;

    // prologue: step 0 loads
    bf16x8 af = aptr[0];
    float r0 = pre[0], r1 = pre[NN], r2 = pre[2 * NN], r3 = pre[3 * NN];
    float i0 = pim[0], i1 = pim[NN], i2 = pim[2 * NN], i3 = pim[3 * NN];

    for (int t = 0; t < steps - 1; ++t) {
        // issue step t+1 loads first (latency overlapped with pack+MFMA below)
        bf16x8 afn = aptr[(size_t)(2 * (t + 1)) * 32];
        const float* prn = pre + (size_t)(t + 1) * 8 * NN;
        const float* pin = pim + (size_t)(t + 1) * 8 * NN;
        float r0n = prn[0], r1n = prn[NN], r2n = prn[2 * NN], r3n = prn[3 * NN];
        float i0n = pin[0], i1n = pin[NN], i2n = pin[2 * NN], i3n = pin[3 * NN];

        // pack + MFMA step t
        uint32_t R0 = f2bf(r0), R1 = f2bf(r1), R2 = f2bf(r2), R3 = f2bf(r3);
        uint32_t I0 = f2bf(i0), I1 = f2bf(i1), I2 = f2bf(i2), I3 = f2bf(i3);
        union { bf16x8 v; uint32_t d[4]; } uR, uI;
        uR.d[0] = R0 | ((I0 ^ 0x8000u) << 16);  uI.d[0] = I0 | (R0 << 16);
        uR.d[1] = R1 | ((I1 ^ 0x8000u) << 16);  uI.d[1] = I1 | (R1 << 16);
        uR.d[2] = R2 | ((I2 ^ 0x8000u) << 16);  uI.d[2] = I2 | (R2 << 16);
        uR.d[3] = R3 | ((I3 ^ 0x8000u) << 16);  uI.d[3] = I3 | (R3 << 16);
        accR = __builtin_amdgcn_mfma_f32_32x32x16_bf16(af, uR.v, accR, 0, 0, 0);
        accI = __builtin_amdgcn_mfma_f32_32x32x16_bf16(af, uI.v, accI, 0, 0, 0);

        // rotate
        af = afn;
        r0 = r0n; r1 = r1n; r2 = r2n; r3 = r3n;
        i0 = i0n; i1 = i1n; i2 = i2n; i3 = i3n;
    }

    // epilogue: last step
    {
        uint32_t R0 = f2bf(r0), R1 = f2bf(r1), R2 = f2bf(r2), R3 = f2bf(r3);
        uint32_t I0 = f2bf(i0), I1 = f2bf(i1), I2 = f2bf(i2), I3 = f2bf(i3);
        union { bf16x8 v; uint32_t d[4]; } uR, uI;
        uR.d[0] = R0 | ((I0 ^ 0x8000u) << 16);  uI.d[0] = I0 | (R0 << 16);
        uR.d[1] = R1 | ((I1 ^ 0x8000u) << 16);  uI.d[1] = I1 | (R1 << 16);
        uR.d[2] = R2 | ((I2 ^ 0x8000u) << 16);  uI.d[2] = I2 | (R2 << 16);
        uR.d[3] = R3 | ((I3 ^ 0x8000u) << 16);  uI.d[3] = I3 | (R3 << 16);
        accR = __builtin_amdgcn_mfma_f32_32x32x16_bf16(af, uR.v, accR, 0, 0, 0);
        accI = __builtin_amdgcn_mfma_f32_32x32x16_bf16(af, uI.v, accI, 0, 0, 0);
    }

    // C/D layout (32x32, verified): col = lane&31 (=n),
    // row(batch) = (reg&3) + 8*(reg>>2) + 4*h
#pragma unroll
    for (int r = 0; r < 16; ++r) {
        int brow = (r & 3) + 8 * (r >> 2) + 4 * h;
        float2 v; v.x = accR[r]; v.y = accI[r];
        wsP[((size_t)s * NB + brow) * NN + n] = v;
    }
}

// ---------------------------------------------------------------------------
// Kernel 3: planar output (proven R5): out[b*4096+n]=re, out[HALF+..]=im
// ---------------------------------------------------------------------------
__global__ __launch_bounds__(256) void reduce_kernel(
    const float2* __restrict__ wsP, float* __restrict__ out, int S)
{
    int tid = blockIdx.x * 256 + threadIdx.x;   // 131072 complex
    float re = 0.f, im = 0.f;
    for (int s = 0; s < S; ++s) {
        float2 v = wsP[(size_t)s * (NB * NN) + tid];
        re += v.x; im += v.y;
    }
    out[tid]        = re;
    out[HALF + tid] = im;
}

extern "C" void kernel_launch(void* const* d_in, const int* in_sizes, int n_in,
                              void* d_out, int out_size, void* d_ws, size_t ws_size,
                              hipStream_t stream)
{
    const float* in_re  = (const float*)d_in[0];
    const float* in_im  = (const float*)d_in[1];
    const float* w_re   = (const float*)d_in[2];
    const float* w_im   = (const float*)d_in[3];
    const float* amp    = (const float*)d_in[4];
    const float* phase  = (const float*)d_in[5];

    const size_t A_BYTES = (size_t)1024 * 32 * 16;   // 512 KB bf16 A-fragments
    uint32_t* wsA = (uint32_t*)d_ws;
    float2*   wsP = (float2*)((char*)d_ws + A_BYTES);

    // largest split-K whose fp32 partial buffer fits the workspace
    int S = 32;
    while (S > 1 && A_BYTES + (size_t)S * NB * NN * sizeof(float2) > ws_size) S >>= 1;
    int steps = (KC / S) / 8;

    prep_kernel<<<dim3((NB * KC) / 256), dim3(256), 0, stream>>>(
        in_re, in_im, amp, phase, wsA);

    gemm_kernel<<<dim3(NN / 128, S), dim3(256), 0, stream>>>(
        w_re, w_im, (const bf16x8*)wsA, wsP, steps);

    reduce_kernel<<<dim3((NB * NN) / 256), dim3(256), 0, stream>>>(
        wsP, (float*)d_out, S);
}

// Round 8
// 172.962 us; speedup vs baseline: 1.0061x; 1.0061x over previous
//
#include <hip/hip_runtime.h>
#include <cstdint>
#include <cstddef>

// B=32 batch, K=4096 complex input pixels, N=4096 complex outputs.
// out[b,n] = sum_k (e_in[b,k]*ts[k]) * w[k,n]   (complex)
// Real-GEMM formulation, K'=8192 interleaved (re,im). Verified bits (R5-R7):
//  - A-fragment octet packing in wsA, 32x32x16 C/D layout, planar fp32 output.
#define KC 4096
#define NN 4096
#define NB 32
#define HALF (NB * NN)
#define S_SPLIT 32            // split-K factor (R7 proved 32MB partials fit ws)
#define KSP (KC / S_SPLIT)    // 128 complex k per split
#define CK 32                 // complex k per LDS chunk
#define NCHUNK (KSP / CK)     // 4 chunks per split
#define CSTEPS (CK / 8)       // 4 MFMA steps per chunk (8 complex k each)

typedef __attribute__((ext_vector_type(8))) short  bf16x8;  // 8 bf16 (4 VGPRs)
typedef __attribute__((ext_vector_type(16))) float f32x16;  // 32x32 MFMA acc

__device__ __forceinline__ uint32_t f2bf(float f) {
    // round-to-nearest-even fp32 -> bf16, low 16 bits
    union { float f; unsigned u; } v; v.f = f;
    unsigned r = v.u + 0x7fffu + ((v.u >> 16) & 1u);
    return r >> 16;
}

// async global->LDS DMA, 16B per lane; LDS dst = wave-uniform base + lane*16
__device__ __forceinline__ void load_lds16(const float* g, float* lds) {
    __builtin_amdgcn_global_load_lds(
        (const __attribute__((address_space(1))) void*)g,
        (__attribute__((address_space(3))) void*)lds, 16, 0, 0);
}

// ---------------------------------------------------------------------------
// Kernel 1: modulated[b,k] = e_in[b,k] * (sigmoid(amp[k]) * exp(i*phase[k]))
// bf16 pairs in MFMA-A octet order (verified): dword idx = ((k>>2)*32+b)*4+(k&3)
// ---------------------------------------------------------------------------
__global__ __launch_bounds__(256) void prep_kernel(
    const float* __restrict__ in_re, const float* __restrict__ in_im,
    const float* __restrict__ amp,   const float* __restrict__ phase,
    uint32_t* __restrict__ wsA)
{
    int tid = blockIdx.x * 256 + threadIdx.x;   // 32*4096 threads
    int b = tid >> 12;
    int k = tid & (KC - 1);
    float er = in_re[tid], ei = in_im[tid];
    float a = amp[k], p = phase[k];
    float s = 1.0f / (1.0f + expf(-a));
    float sn, cs;
    sincosf(p, &sn, &cs);
    float tr = s * cs, ti = s * sn;
    float mr = er * tr - ei * ti;
    float mi = er * ti + ei * tr;
    uint32_t pk = f2bf(mr) | (f2bf(mi) << 16);
    wsA[((((k >> 2) << 5) + b) << 2) | (k & 3)] = pk;
}

// ---------------------------------------------------------------------------
// Kernel 2: split-K complex GEMM. W staged via global_load_lds dwordx4 into
// 32KB LDS chunks ([plane][row 0..31][col 0..127] fp32); B-frags read from
// LDS (conflict-free: lane->col), 2x mfma_f32_32x32x16_bf16 per 8 complex k.
// Block = 4 waves x 32 cols = 128-col tile, all 32 batches.
// ---------------------------------------------------------------------------
__global__ __launch_bounds__(256, 4) void gemm_kernel(
    const float* __restrict__ w_re, const float* __restrict__ w_im,
    const bf16x8* __restrict__ wsA, float2* __restrict__ wsP)
{
    __shared__ float shW[2 * CK * 128];   // 32 KB: plane*4096 + row*128 + col
    const int lane = threadIdx.x & 63;
    const int wave = threadIdx.x >> 6;
    const int h    = lane >> 5;          // K'-octet half
    const int l32  = lane & 31;
    const int c32  = wave * 32 + l32;    // column within 128-tile
    const int n0   = blockIdx.x * 128;
    const int n    = n0 + c32;
    const int s    = blockIdx.y;
    const int kbase = s * KSP;

    // staging lane geometry: each global_load_lds covers 2 rows x 128 cols
    const int srow = lane >> 5;
    const int scol = (lane & 31) * 4;

    f32x16 accR = {}, accI = {};

#pragma unroll
    for (int c = 0; c < NCHUNK; ++c) {
        // A-frags for this chunk (L1/L2-hot wsA; latency hides under DMA wait)
        bf16x8 a[CSTEPS];
#pragma unroll
        for (int st = 0; st < CSTEPS; ++st) {
            int m = c * CSTEPS + st;     // global MFMA step
            a[st] = wsA[((size_t)(kbase >> 2) + 2 * m + h) * 32 + l32];
        }

        // stage chunk c: 32 segments of 1KB (2 rows of one plane each);
        // wave issues segments wave*8 .. wave*8+7
        const int krow0 = kbase + c * CK;
#pragma unroll
        for (int i = 0; i < 8; ++i) {
            int seg = wave * 8 + i;                  // 0..31 (wave-uniform)
            const float* wp = (seg < 16) ? w_re : w_im;
            int rp = seg & 15;                       // row-pair within chunk
            const float* g = wp + (size_t)(krow0 + 2 * rp + srow) * NN
                                + (n0 + scol);
            load_lds16(g, &shW[seg * 256]);
        }
        asm volatile("s_waitcnt vmcnt(0)" ::: "memory");
        __syncthreads();

#pragma unroll
        for (int st = 0; st < CSTEPS; ++st) {
            int rb = st * 8 + h * 4;    // chunk-local complex-k row base
            float r0 = shW[(rb + 0) * 128 + c32];
            float r1 = shW[(rb + 1) * 128 + c32];
            float r2 = shW[(rb + 2) * 128 + c32];
            float r3 = shW[(rb + 3) * 128 + c32];
            float i0 = shW[4096 + (rb + 0) * 128 + c32];
            float i1 = shW[4096 + (rb + 1) * 128 + c32];
            float i2 = shW[4096 + (rb + 2) * 128 + c32];
            float i3 = shW[4096 + (rb + 3) * 128 + c32];

            uint32_t R0 = f2bf(r0), R1 = f2bf(r1), R2 = f2bf(r2), R3 = f2bf(r3);
            uint32_t I0 = f2bf(i0), I1 = f2bf(i1), I2 = f2bf(i2), I3 = f2bf(i3);
            union { bf16x8 v; uint32_t d[4]; } uR, uI;
            uR.d[0] = R0 | ((I0 ^ 0x8000u) << 16);  uI.d[0] = I0 | (R0 << 16);
            uR.d[1] = R1 | ((I1 ^ 0x8000u) << 16);  uI.d[1] = I1 | (R1 << 16);
            uR.d[2] = R2 | ((I2 ^ 0x8000u) << 16);  uI.d[2] = I2 | (R2 << 16);
            uR.d[3] = R3 | ((I3 ^ 0x8000u) << 16);  uI.d[3] = I3 | (R3 << 16);
            accR = __builtin_amdgcn_mfma_f32_32x32x16_bf16(a[st], uR.v, accR, 0, 0, 0);
            accI = __builtin_amdgcn_mfma_f32_32x32x16_bf16(a[st], uI.v, accI, 0, 0, 0);
        }
        __syncthreads();   // protect chunk buffer before next stage
    }

    // C/D layout (32x32, verified): col = lane&31 (=n),
    // row(batch) = (reg&3) + 8*(reg>>2) + 4*h
#pragma unroll
    for (int r = 0; r < 16; ++r) {
        int brow = (r & 3) + 8 * (r >> 2) + 4 * h;
        float2 v; v.x = accR[r]; v.y = accI[r];
        wsP[((size_t)s * NB + brow) * NN + n] = v;
    }
}

// ---------------------------------------------------------------------------
// Kernel 3: planar output (proven): out[b*4096+n]=re, out[HALF+..]=im
// ---------------------------------------------------------------------------
__global__ __launch_bounds__(256) void reduce_kernel(
    const float2* __restrict__ wsP, float* __restrict__ out, int S)
{
    int tid = blockIdx.x * 256 + threadIdx.x;   // 131072 complex
    float re = 0.f, im = 0.f;
    for (int s = 0; s < S; ++s) {
        float2 v = wsP[(size_t)s * (NB * NN) + tid];
        re += v.x; im += v.y;
    }
    out[tid]        = re;
    out[HALF + tid] = im;
}

extern "C" void kernel_launch(void* const* d_in, const int* in_sizes, int n_in,
                              void* d_out, int out_size, void* d_ws, size_t ws_size,
                              hipStream_t stream)
{
    const float* in_re  = (const float*)d_in[0];
    const float* in_im  = (const float*)d_in[1];
    const float* w_re   = (const float*)d_in[2];
    const float* w_im   = (const float*)d_in[3];
    const float* amp    = (const float*)d_in[4];
    const float* phase  = (const float*)d_in[5];

    const size_t A_BYTES = (size_t)1024 * 32 * 16;   // 512 KB bf16 A-fragments
    uint32_t* wsA = (uint32_t*)d_ws;
    float2*   wsP = (float2*)((char*)d_ws + A_BYTES);
    // S_SPLIT=32 partials = 32 MB; R7's WRITE_SIZE=32MB proved this fits ws.

    prep_kernel<<<dim3((NB * KC) / 256), dim3(256), 0, stream>>>(
        in_re, in_im, amp, phase, wsA);

    gemm_kernel<<<dim3(NN / 128, S_SPLIT), dim3(256), 0, stream>>>(
        w_re, w_im, (const bf16x8*)wsA, wsP);

    reduce_kernel<<<dim3((NB * NN) / 256), dim3(256), 0, stream>>>(
        wsP, (float*)d_out, S_SPLIT);
}